// Round 5
// baseline (513.248 us; speedup 1.0000x reference)
//
#include <hip/hip_runtime.h>
#include <hip/hip_bf16.h>

#define LWAV   480000
#define XPADL  481024
#define NBATCH 32
#define TOUT   1000
#define NFFT   1024
#define NBINS  513
#define NMEL   64
#define PWC    512
#define SPECW  1024
#define HOP    480

// workspace layout (bytes), 256-aligned
#define XPAD_OFF 0u           // 32*481024*2   = 30,785,536
#define WB_OFF   30785536u    // 1026*1024*2   =  2,101,248
#define WMT_OFF  32886784u    // 64*512*2      =     65,536
#define PW_OFF   32952320u    // 32000*512*2   = 32,768,000
#define LM_OFF   65720320u    // 32000*64*4    =  8,192,000
#define P512_OFF 73912320u    // 32000*4       =    128,000  -> end 74,040,320

typedef __attribute__((ext_vector_type(8))) __bf16 bf16x8;
typedef __attribute__((ext_vector_type(8))) unsigned short ushort8;
typedef __attribute__((ext_vector_type(4))) float  f32x4;

__device__ __forceinline__ void gload16(const void* g, void* l) {
  __builtin_amdgcn_global_load_lds((const __attribute__((address_space(1))) void*)g,
                                   (__attribute__((address_space(3))) void*)l, 16, 0, 0);
}

#define WAIT_VM(n)  asm volatile("s_waitcnt vmcnt(" #n ")" ::: "memory")
#define WAIT_LGKM0  asm volatile("s_waitcnt lgkmcnt(0)" ::: "memory")
#define BAR() __builtin_amdgcn_s_barrier()

__device__ __forceinline__ float bf2f(unsigned short u) {
  return __uint_as_float((unsigned)u << 16);
}

// ---------------- prepass ----------------
#define NV1 (NBATCH * (XPADL / 8))          // 1,924,096
#define NV2 ((1026 * NFFT) / 8)             //   131,328
#define NV3 ((NMEL * PWC) / 8)              //     4,096

__global__ void prep_kernel(const float* __restrict__ wav,
                            const float* __restrict__ wstft,
                            const float* __restrict__ mf,
                            unsigned char* __restrict__ ws) {
  __hip_bfloat16* xpad = (__hip_bfloat16*)(ws + XPAD_OFF);
  __hip_bfloat16* wb   = (__hip_bfloat16*)(ws + WB_OFF);
  __hip_bfloat16* wmt  = (__hip_bfloat16*)(ws + WMT_OFF);
  int idx = blockIdx.x * blockDim.x + threadIdx.x;
  if (idx < NV1) {
    int b  = idx / (XPADL / 8);
    int pg = (idx - b * (XPADL / 8)) * 8;
    __hip_bfloat16* dst = xpad + (size_t)b * XPADL + pg;
    const float* src = wav + (size_t)b * LWAV;
    if (pg >= 512 && pg <= LWAV + 496) {
      float4 v0 = *(const float4*)(src + pg - 512);
      float4 v1 = *(const float4*)(src + pg - 508);
      __hip_bfloat16 t[8];
      t[0] = __float2bfloat16(v0.x); t[1] = __float2bfloat16(v0.y);
      t[2] = __float2bfloat16(v0.z); t[3] = __float2bfloat16(v0.w);
      t[4] = __float2bfloat16(v1.x); t[5] = __float2bfloat16(v1.y);
      t[6] = __float2bfloat16(v1.z); t[7] = __float2bfloat16(v1.w);
      *(uint4*)dst = *(const uint4*)t;
    } else {
      for (int j = 0; j < 8; ++j) {
        int s = pg + j - 512;
        if (s < 0) s = -s;
        else if (s >= LWAV) s = 2 * (LWAV - 1) - s;
        dst[j] = __float2bfloat16(src[s]);
      }
    }
  } else if (idx < NV1 + NV2) {
    int g = (idx - NV1) * 8;
    float4 v0 = *(const float4*)(wstft + g);
    float4 v1 = *(const float4*)(wstft + g + 4);
    __hip_bfloat16 t[8];
    t[0] = __float2bfloat16(v0.x); t[1] = __float2bfloat16(v0.y);
    t[2] = __float2bfloat16(v0.z); t[3] = __float2bfloat16(v0.w);
    t[4] = __float2bfloat16(v1.x); t[5] = __float2bfloat16(v1.y);
    t[6] = __float2bfloat16(v1.z); t[7] = __float2bfloat16(v1.w);
    *(uint4*)(wb + g) = *(const uint4*)t;
  } else if (idx < NV1 + NV2 + NV3) {
    int j  = idx - NV1 - NV2;
    int n  = j / (PWC / 8);
    int k0 = (j - n * (PWC / 8)) * 8;
    for (int k = k0; k < k0 + 8; ++k)
      wmt[n * PWC + k] = __float2bfloat16(mf[k * NMEL + n]);
  }
}

// ---------------- p512: power of bin 512 per frame (no LDS, direct L2/L3 reads) ----
// grid 32*16; block 256; 64 frames/block (last tile 40). 16 lanes per frame.
__launch_bounds__(256, 4)
__global__ void p512_kernel(unsigned char* __restrict__ ws) {
  const unsigned char* xpadb = ws + XPAD_OFF;
  const unsigned char* wbb   = ws + WB_OFF;
  float* out = (float*)(ws + P512_OFF);

  const int tid  = threadIdx.x;
  const int b    = blockIdx.x >> 4;
  const int tile = blockIdx.x & 15;
  const int t0   = tile * 64;
  const int nf   = (tile == 15) ? 40 : 64;

  const int lane = tid & 63;
  const int wv   = tid >> 6;
  const int kc   = lane & 15;
  const int fg   = lane >> 4;
  const unsigned char* wc_base = wbb + (size_t)512  * 2048 + kc * 16;
  const unsigned char* ws_base = wbb + (size_t)1025 * 2048 + kc * 16;
#pragma unroll
  for (int pass = 0; pass < 4; ++pass) {
    int fr = pass * 16 + wv * 4 + fg;
    if (fr < nf) {
      const unsigned char* xp = xpadb + ((size_t)b * XPADL + (size_t)(t0 + fr) * HOP) * 2 + kc * 16;
      float dc = 0.f, dsn = 0.f;
#pragma unroll
      for (int j = 0; j < 8; ++j) {
        ushort8 a  = *(const ushort8*)(xp + j * 256);
        ushort8 uc = *(const ushort8*)(wc_base + j * 256);
        ushort8 us = *(const ushort8*)(ws_base + j * 256);
#pragma unroll
        for (int e = 0; e < 8; ++e) {
          float fa = bf2f(a[e]);
          dc  += fa * bf2f(uc[e]);
          dsn += fa * bf2f(us[e]);
        }
      }
#pragma unroll
      for (int d = 1; d < 16; d <<= 1) {
        dc  += __shfl_xor(dc, d);
        dsn += __shfl_xor(dsn, d);
      }
      if (kc == 0)
        out[(size_t)b * TOUT + t0 + fr] = dc * dc + dsn * dsn;
    }
  }
}

// ---------------- STFT: 256x256 MFMA GEMM, register-double-buffered fragment
// prefetch (1 ktile/iteration), counted vmcnt, + power epilogue ----
// BM=256 frames, BN=256 weight rows (128 bins x {cos,sin}: row n -> bin =
// bin0+(n>>5)*16+(n&15), part=(n>>4)&1). 8 waves (2M x 4N), BK=64, 16 ktiles.
// Per iter: stage k(i+2)->LDS[i&1]; WAIT_VM(8); BAR; RD k(i+1)->regs[nxt];
// MFMA k(i) from regs[cur] (overlaps the just-issued ds_reads); lgkm0; BAR.
#define STFT_NWG 500
__launch_bounds__(512, 1)
__global__ void stft_kernel(unsigned char* __restrict__ ws) {
  __shared__ __align__(16) unsigned char lds[131072];  // A: c*32768; B: 65536+c*32768
  const unsigned char* xpadb = ws + XPAD_OFF;
  const unsigned char* wbb   = ws + WB_OFF;
  __hip_bfloat16* pw = (__hip_bfloat16*)(ws + PW_OFF);

  const int tid  = threadIdx.x;
  const int lane = tid & 63;
  const int w    = tid >> 6;
  const int wm   = w >> 2;
  const int wc   = w & 3;

  // bijective XCD-chunked swizzle (nwg=500: q=62, r=4), n-tile fastest
  const int orig = blockIdx.x;
  const int q8 = STFT_NWG / 8, r8 = STFT_NWG % 8;
  const int xcd = orig & 7;
  const int wg = (xcd < r8 ? xcd * (q8 + 1) : r8 * (q8 + 1) + (xcd - r8) * q8) + (orig >> 3);
  const int bin0 = (wg & 3) * 128;
  const int m0   = (wg >> 2) * 256;

  // staging sources (pre-swizzled col; involution XOR on bits 4..6)
  const int srow = tid >> 3;          // 0..63 row within a 64-row quarter
  const int scol = (tid & 7) << 4;
  const unsigned char *gA0, *gA1, *gA2, *gA3, *gB0, *gB1, *gB2, *gB3;
  {
    int r0 = srow, r1 = 64 + srow, r2 = 128 + srow, r3 = 192 + srow;
    int m, bb, tt;
    m = m0 + r0; bb = m / 1000; tt = m - bb * 1000;
    gA0 = xpadb + ((size_t)bb * XPADL + (size_t)tt * HOP) * 2 + (scol ^ ((r0 & 7) << 4));
    m = m0 + r1; bb = m / 1000; tt = m - bb * 1000;
    gA1 = xpadb + ((size_t)bb * XPADL + (size_t)tt * HOP) * 2 + (scol ^ ((r1 & 7) << 4));
    m = m0 + r2; bb = m / 1000; tt = m - bb * 1000;
    gA2 = xpadb + ((size_t)bb * XPADL + (size_t)tt * HOP) * 2 + (scol ^ ((r2 & 7) << 4));
    m = m0 + r3; bb = m / 1000; tt = m - bb * 1000;
    gA3 = xpadb + ((size_t)bb * XPADL + (size_t)tt * HOP) * 2 + (scol ^ ((r3 & 7) << 4));
#define BROW(r) ((size_t)(bin0 + (((r) >> 5) << 4) + ((r) & 15) + ((((r) >> 4) & 1) * 513)) * 2048)
    gB0 = wbb + BROW(r0) + (scol ^ ((r0 & 7) << 4));
    gB1 = wbb + BROW(r1) + (scol ^ ((r1 & 7) << 4));
    gB2 = wbb + BROW(r2) + (scol ^ ((r2 & 7) << 4));
    gB3 = wbb + BROW(r3) + (scol ^ ((r3 & 7) << 4));
  }

  // LDS staging dests: c*32768 (A) / 65536+c*32768 (B), quarter qq, wave chunk
#define LDSA(c, qq) ((void*)(lds + (c) * 32768 + (qq) * 8192 + w * 1024))
#define LDSB(c, qq) ((void*)(lds + 65536 + (c) * 32768 + (qq) * 8192 + w * 1024))
#define STG_ALL(c, kb) do {                                                \
    gload16(gA0 + (kb), LDSA(c, 0)); gload16(gA1 + (kb), LDSA(c, 1));      \
    gload16(gA2 + (kb), LDSA(c, 2)); gload16(gA3 + (kb), LDSA(c, 3));      \
    gload16(gB0 + (kb), LDSB(c, 0)); gload16(gB1 + (kb), LDSB(c, 1));      \
    gload16(gB2 + (kb), LDSB(c, 2)); gload16(gB3 + (kb), LDSB(c, 3));      \
  } while (0)

  // hoisted ds_read lane bases (row&7 == lane&7 -> phase-invariant XOR)
  const int xor0 = (((lane >> 4) << 4)) ^ ((lane & 7) << 4);
  const int xor1 = (64 + ((lane >> 4) << 4)) ^ ((lane & 7) << 4);
  const unsigned char* aB0 = lds + wm * 16384 + (lane & 15) * 128 + xor0;
  const unsigned char* aB1 = lds + wm * 16384 + (lane & 15) * 128 + xor1;
  const unsigned char* bB0 = lds + 65536 + wc * 8192 + (lane & 15) * 128 + xor0;
  const unsigned char* bB1 = lds + 65536 + wc * 8192 + (lane & 15) * 128 + xor1;

  bf16x8 af[2][8][2];   // [set][mf][ks]
  bf16x8 bfr[2][4][2];  // [set][nf][ks]
  f32x4 acc[8][4];
#pragma unroll
  for (int a = 0; a < 8; ++a)
#pragma unroll
    for (int b = 0; b < 4; ++b) acc[a][b] = (f32x4){0.f, 0.f, 0.f, 0.f};

#define RD_ALL(CCOFF, S) do {                                              \
    _Pragma("unroll")                                                      \
    for (int mf_ = 0; mf_ < 8; ++mf_) {                                    \
      af[S][mf_][0] = *(const bf16x8*)(aB0 + (CCOFF) + mf_ * 2048);        \
      af[S][mf_][1] = *(const bf16x8*)(aB1 + (CCOFF) + mf_ * 2048);        \
    }                                                                      \
    _Pragma("unroll")                                                      \
    for (int nf_ = 0; nf_ < 4; ++nf_) {                                    \
      bfr[S][nf_][0] = *(const bf16x8*)(bB0 + (CCOFF) + nf_ * 2048);       \
      bfr[S][nf_][1] = *(const bf16x8*)(bB1 + (CCOFF) + nf_ * 2048);       \
    }                                                                      \
  } while (0)

#define MFMA_ALL(S) do {                                                   \
    __builtin_amdgcn_s_setprio(1);                                         \
    _Pragma("unroll")                                                      \
    for (int mf_ = 0; mf_ < 8; ++mf_)                                      \
      _Pragma("unroll")                                                    \
      for (int nf_ = 0; nf_ < 4; ++nf_) {                                  \
        acc[mf_][nf_] = __builtin_amdgcn_mfma_f32_16x16x32_bf16(           \
            af[S][mf_][0], bfr[S][nf_][0], acc[mf_][nf_], 0, 0, 0);        \
        acc[mf_][nf_] = __builtin_amdgcn_mfma_f32_16x16x32_bf16(           \
            af[S][mf_][1], bfr[S][nf_][1], acc[mf_][nf_], 0, 0, 0);        \
      }                                                                    \
    __builtin_amdgcn_s_setprio(0);                                         \
  } while (0)

  // prologue: stage k0->LDS0, k1->LDS1; read k0 -> set0; fence before overwrite
  STG_ALL(0, 0);
  STG_ALL(1, 128);
  WAIT_VM(8);
  BAR();
  RD_ALL(0, 0);
  WAIT_LGKM0;
  BAR();

  for (int ii = 0; ii < 7; ++ii) {
    // i = 2ii: consume set0 (k 2ii); stage k(2ii+2)->LDS0; RD k(2ii+1)->set1
    STG_ALL(0, (size_t)(2 * ii + 2) * 128);
    WAIT_VM(8);
    BAR();
    RD_ALL(32768, 1);
    MFMA_ALL(0);
    WAIT_LGKM0;
    BAR();
    // i = 2ii+1: consume set1; stage k(2ii+3)->LDS1; RD k(2ii+2)->set0
    STG_ALL(1, (size_t)(2 * ii + 3) * 128);
    WAIT_VM(8);
    BAR();
    RD_ALL(0, 0);
    MFMA_ALL(1);
    WAIT_LGKM0;
    BAR();
  }
  // i=14: consume set0 (k14); RD k15 (LDS1) -> set1 (no stage left)
  WAIT_VM(0);
  BAR();
  RD_ALL(32768, 1);
  MFMA_ALL(0);
  // i=15: consume set1 (k15)
  MFMA_ALL(1);

  // epilogue: power = cos^2 + sin^2 (nf pairs (0,1),(2,3))
  const int col = lane & 15;
  const int rg  = lane >> 4;
#pragma unroll
  for (int mf_ = 0; mf_ < 8; ++mf_)
#pragma unroll
    for (int g = 0; g < 2; ++g) {
      int bin = bin0 + wc * 32 + g * 16 + col;
#pragma unroll
      for (int rr = 0; rr < 4; ++rr) {
        int m = m0 + wm * 128 + mf_ * 16 + rg * 4 + rr;
        float c = acc[mf_][2 * g][rr];
        float s = acc[mf_][2 * g + 1][rr];
        pw[(size_t)m * PWC + bin] = __float2bfloat16(c * c + s * s);
      }
    }
}

// ---------------- mel GEMM (K=512) + p512 rank-1 + log10 epilogue ----------------
__launch_bounds__(256, 2)
__global__ void mel_kernel(unsigned char* __restrict__ ws, const float* __restrict__ mfp) {
  __shared__ __align__(16) unsigned char sA[128 * 128];
  __shared__ __align__(16) unsigned char sBt[64 * 128];
  const unsigned char* pwb  = ws + PW_OFF;
  const unsigned char* wmtb = ws + WMT_OFF;
  const float* p5 = (const float*)(ws + P512_OFF);
  float* lm = (float*)(ws + LM_OFF);

  const int tid = threadIdx.x;
  const int lane = tid & 63;
  const int wid  = tid >> 6;
  const int m0 = blockIdx.x * 128;

  const int srow = lane >> 3;
  const int kb2  = (lane & 7) << 4;

  const unsigned char* aptr[4];
  unsigned char* aldst[4];
#pragma unroll
  for (int j = 0; j < 4; ++j) {
    int rr = wid * 32 + j * 8 + srow;
    aptr[j] = pwb + (size_t)(m0 + rr) * (PWC * 2) + (kb2 ^ ((rr & 7) << 4));
    aldst[j] = &sA[(wid * 32 + j * 8) * 128];
  }
  const unsigned char* bptr[2];
  unsigned char* bldst[2];
#pragma unroll
  for (int j = 0; j < 2; ++j) {
    int rr = wid * 16 + j * 8 + srow;
    bptr[j] = wmtb + (size_t)rr * (PWC * 2) + (kb2 ^ ((rr & 7) << 4));
    bldst[j] = &sBt[(wid * 16 + j * 8) * 128];
  }

  f32x4 acc[2][4];
#pragma unroll
  for (int mi = 0; mi < 2; ++mi)
#pragma unroll
    for (int fr = 0; fr < 4; ++fr) acc[mi][fr] = (f32x4){0.f, 0.f, 0.f, 0.f};

  for (int kk = 0; kk < PWC; kk += 64) {
    __syncthreads();
#pragma unroll
    for (int j = 0; j < 4; ++j) gload16(aptr[j] + (size_t)kk * 2, aldst[j]);
#pragma unroll
    for (int j = 0; j < 2; ++j) gload16(bptr[j] + (size_t)kk * 2, bldst[j]);
    __syncthreads();
#pragma unroll
    for (int ks = 0; ks < 2; ++ks) {
      const int kby = ks * 64 + ((lane >> 4) << 4);
      bf16x8 af[2], bfr[4];
#pragma unroll
      for (int mi = 0; mi < 2; ++mi) {
        int rr = wid * 32 + mi * 16 + (lane & 15);
        af[mi] = *(const bf16x8*)&sA[rr * 128 + (kby ^ ((rr & 7) << 4))];
      }
#pragma unroll
      for (int fr = 0; fr < 4; ++fr) {
        int rr = fr * 16 + (lane & 15);
        bfr[fr] = *(const bf16x8*)&sBt[rr * 128 + (kby ^ ((rr & 7) << 4))];
      }
#pragma unroll
      for (int mi = 0; mi < 2; ++mi)
#pragma unroll
        for (int fr = 0; fr < 4; ++fr)
          acc[mi][fr] = __builtin_amdgcn_mfma_f32_16x16x32_bf16(af[mi], bfr[fr], acc[mi][fr], 0, 0, 0);
    }
  }

  const int col = lane & 15;
  const int rg  = lane >> 4;
#pragma unroll
  for (int mi = 0; mi < 2; ++mi)
#pragma unroll
    for (int fr = 0; fr < 4; ++fr) {
      int n = fr * 16 + col;
      float f512 = mfp[512 * NMEL + n];
#pragma unroll
      for (int rr = 0; rr < 4; ++rr) {
        int mrow = wid * 32 + mi * 16 + rg * 4 + rr;
        float v = acc[mi][fr][rr] + p5[m0 + mrow] * f512;
        lm[(size_t)(m0 + mrow) * NMEL + n] = 10.0f * log10f(fmaxf(v, 1e-10f));
      }
    }
}

// ---------------- bilinear (time-axis only) interp ----------------
__global__ void interp_kernel(const unsigned char* __restrict__ ws, float* __restrict__ out) {
  const float* lm = (const float*)(ws + LM_OFF);
  int idx = blockIdx.x * blockDim.x + threadIdx.x;
  if (idx >= NBATCH * SPECW * 16) return;
  int m4 = idx & 15;
  int h  = (idx >> 4) & (SPECW - 1);
  int b  = idx >> 14;
  const float scale = (float)(999.0 / 1023.0);
  float pos = (float)h * scale;
  int i0 = (int)floorf(pos);
  if (i0 > TOUT - 1) i0 = TOUT - 1;
  float w = pos - (float)i0;
  int i1 = i0 + 1;
  if (i1 > TOUT - 1) i1 = TOUT - 1;
  const float4* r0 = (const float4*)(lm + ((size_t)b * TOUT + i0) * NMEL);
  const float4* r1 = (const float4*)(lm + ((size_t)b * TOUT + i1) * NMEL);
  float4 a = r0[m4], c = r1[m4];
  float4 o;
  o.x = a.x * (1.0f - w) + c.x * w;
  o.y = a.y * (1.0f - w) + c.y * w;
  o.z = a.z * (1.0f - w) + c.z * w;
  o.w = a.w * (1.0f - w) + c.w * w;
  ((float4*)out)[idx] = o;
}

extern "C" void kernel_launch(void* const* d_in, const int* in_sizes, int n_in,
                              void* d_out, int out_size, void* d_ws, size_t ws_size,
                              hipStream_t stream) {
  (void)in_sizes; (void)n_in; (void)out_size; (void)ws_size;
  const float* wav   = (const float*)d_in[0];
  const float* wstft = (const float*)d_in[1];
  const float* mf    = (const float*)d_in[2];
  unsigned char* ws  = (unsigned char*)d_ws;
  float* out = (float*)d_out;

  const int tot = NV1 + NV2 + NV3;
  prep_kernel<<<(tot + 255) / 256, 256, 0, stream>>>(wav, wstft, mf, ws);
  p512_kernel<<<NBATCH * 16, 256, 0, stream>>>(ws);
  stft_kernel<<<STFT_NWG, 512, 0, stream>>>(ws);
  mel_kernel<<<250, 256, 0, stream>>>(ws, mf);
  interp_kernel<<<(NBATCH * SPECW * 16) / 256, 256, 0, stream>>>(ws, out);
}

// Round 6
// 130.297 us; speedup vs baseline: 3.9391x; 3.9391x over previous
//
#include <hip/hip_runtime.h>
#include <hip/hip_bf16.h>

#define LWAV   480000
#define XPADL  481024
#define NBATCH 32
#define TOUT   1000
#define NFFT   1024
#define NBINS  513
#define NMEL   64
#define PWC    512
#define SPECW  1024
#define HOP    480

// workspace layout (bytes), 256-aligned
#define XPAD_OFF 0u           // 32*481024*2   = 30,785,536
#define WB_OFF   30785536u    // 1026*1024*2   =  2,101,248
#define WMT_OFF  32886784u    // 64*512*2      =     65,536
#define PW_OFF   32952320u    // 32000*512*2   = 32,768,000
#define LM_OFF   65720320u    // 32000*64*4    =  8,192,000
#define P512_OFF 73912320u    // 32000*4       =    128,000  -> end 74,040,320

typedef __attribute__((ext_vector_type(8))) __bf16 bf16x8;
typedef __attribute__((ext_vector_type(8))) unsigned short ushort8;
typedef __attribute__((ext_vector_type(4))) float  f32x4;

__device__ __forceinline__ void gload16(const void* g, void* l) {
  __builtin_amdgcn_global_load_lds((const __attribute__((address_space(1))) void*)g,
                                   (__attribute__((address_space(3))) void*)l, 16, 0, 0);
}

#define WAIT_VM(n)  asm volatile("s_waitcnt vmcnt(" #n ")" ::: "memory")
#define WAIT_LGKM0  asm volatile("s_waitcnt lgkmcnt(0)" ::: "memory")
#define BAR() __builtin_amdgcn_s_barrier()

__device__ __forceinline__ float bf2f(unsigned short u) {
  return __uint_as_float((unsigned)u << 16);
}

// ---------------- prepass ----------------
#define NV1 (NBATCH * (XPADL / 8))          // 1,924,096
#define NV2 ((1026 * NFFT) / 8)             //   131,328
#define NV3 ((NMEL * PWC) / 8)              //     4,096

__global__ void prep_kernel(const float* __restrict__ wav,
                            const float* __restrict__ wstft,
                            const float* __restrict__ mf,
                            unsigned char* __restrict__ ws) {
  __hip_bfloat16* xpad = (__hip_bfloat16*)(ws + XPAD_OFF);
  __hip_bfloat16* wb   = (__hip_bfloat16*)(ws + WB_OFF);
  __hip_bfloat16* wmt  = (__hip_bfloat16*)(ws + WMT_OFF);
  int idx = blockIdx.x * blockDim.x + threadIdx.x;
  if (idx < NV1) {
    int b  = idx / (XPADL / 8);
    int pg = (idx - b * (XPADL / 8)) * 8;
    __hip_bfloat16* dst = xpad + (size_t)b * XPADL + pg;
    const float* src = wav + (size_t)b * LWAV;
    if (pg >= 512 && pg <= LWAV + 496) {
      float4 v0 = *(const float4*)(src + pg - 512);
      float4 v1 = *(const float4*)(src + pg - 508);
      __hip_bfloat16 t[8];
      t[0] = __float2bfloat16(v0.x); t[1] = __float2bfloat16(v0.y);
      t[2] = __float2bfloat16(v0.z); t[3] = __float2bfloat16(v0.w);
      t[4] = __float2bfloat16(v1.x); t[5] = __float2bfloat16(v1.y);
      t[6] = __float2bfloat16(v1.z); t[7] = __float2bfloat16(v1.w);
      *(uint4*)dst = *(const uint4*)t;
    } else {
      for (int j = 0; j < 8; ++j) {
        int s = pg + j - 512;
        if (s < 0) s = -s;
        else if (s >= LWAV) s = 2 * (LWAV - 1) - s;
        dst[j] = __float2bfloat16(src[s]);
      }
    }
  } else if (idx < NV1 + NV2) {
    int g = (idx - NV1) * 8;
    float4 v0 = *(const float4*)(wstft + g);
    float4 v1 = *(const float4*)(wstft + g + 4);
    __hip_bfloat16 t[8];
    t[0] = __float2bfloat16(v0.x); t[1] = __float2bfloat16(v0.y);
    t[2] = __float2bfloat16(v0.z); t[3] = __float2bfloat16(v0.w);
    t[4] = __float2bfloat16(v1.x); t[5] = __float2bfloat16(v1.y);
    t[6] = __float2bfloat16(v1.z); t[7] = __float2bfloat16(v1.w);
    *(uint4*)(wb + g) = *(const uint4*)t;
  } else if (idx < NV1 + NV2 + NV3) {
    int j  = idx - NV1 - NV2;
    int n  = j / (PWC / 8);
    int k0 = (j - n * (PWC / 8)) * 8;
    for (int k = k0; k < k0 + 8; ++k)
      wmt[n * PWC + k] = __float2bfloat16(mf[k * NMEL + n]);
  }
}

// ---------------- p512: power of bin 512 per frame (no LDS, direct L2/L3 reads) ----
__launch_bounds__(256, 4)
__global__ void p512_kernel(unsigned char* __restrict__ ws) {
  const unsigned char* xpadb = ws + XPAD_OFF;
  const unsigned char* wbb   = ws + WB_OFF;
  float* out = (float*)(ws + P512_OFF);

  const int tid  = threadIdx.x;
  const int b    = blockIdx.x >> 4;
  const int tile = blockIdx.x & 15;
  const int t0   = tile * 64;
  const int nf   = (tile == 15) ? 40 : 64;

  const int lane = tid & 63;
  const int wv   = tid >> 6;
  const int kc   = lane & 15;
  const int fg   = lane >> 4;
  const unsigned char* wc_base = wbb + (size_t)512  * 2048 + kc * 16;
  const unsigned char* ws_base = wbb + (size_t)1025 * 2048 + kc * 16;
#pragma unroll
  for (int pass = 0; pass < 4; ++pass) {
    int fr = pass * 16 + wv * 4 + fg;
    if (fr < nf) {
      const unsigned char* xp = xpadb + ((size_t)b * XPADL + (size_t)(t0 + fr) * HOP) * 2 + kc * 16;
      float dc = 0.f, dsn = 0.f;
#pragma unroll
      for (int j = 0; j < 8; ++j) {
        ushort8 a  = *(const ushort8*)(xp + j * 256);
        ushort8 uc = *(const ushort8*)(wc_base + j * 256);
        ushort8 us = *(const ushort8*)(ws_base + j * 256);
#pragma unroll
        for (int e = 0; e < 8; ++e) {
          float fa = bf2f(a[e]);
          dc  += fa * bf2f(uc[e]);
          dsn += fa * bf2f(us[e]);
        }
      }
#pragma unroll
      for (int d = 1; d < 16; d <<= 1) {
        dc  += __shfl_xor(dc, d);
        dsn += __shfl_xor(dsn, d);
      }
      if (kc == 0)
        out[(size_t)b * TOUT + t0 + fr] = dc * dc + dsn * dsn;
    }
  }
}

// ---------------- STFT: 256x256 MFMA GEMM, 2-barrier-per-ktile counted-vmcnt ----
// BM=256 frames, BN=256 weight rows (128 bins x {cos,sin}: row n -> bin =
// bin0+(n>>5)*16+(n&15), part=(n>>4)&1). 8 waves (2M x 4N), BK=64, 16 ktiles,
// dbuf LDS 128 KiB. Per ktile: RD 24 frags; lgkm0; BAR; STG k+2 -> same buf;
// 64 MFMA (pipe overlaps next iter's RDs across the vm-wait barrier); vm(8); BAR.
// Single fragment set: 96 frag VGPR + 128 acc AGPR + addr ~= fits 256/wave.
#define STFT_NWG 500
__launch_bounds__(512, 1)
__global__ void stft_kernel(unsigned char* __restrict__ ws) {
  __shared__ __align__(16) unsigned char lds[131072];  // A: c*32768; B: 65536+c*32768
  const unsigned char* xpadb = ws + XPAD_OFF;
  const unsigned char* wbb   = ws + WB_OFF;
  __hip_bfloat16* pw = (__hip_bfloat16*)(ws + PW_OFF);

  const int tid  = threadIdx.x;
  const int lane = tid & 63;
  const int w    = tid >> 6;
  const int wm   = w >> 2;
  const int wc   = w & 3;

  // bijective XCD-chunked swizzle (nwg=500: q=62, r=4), n-tile fastest
  const int orig = blockIdx.x;
  const int q8 = STFT_NWG / 8, r8 = STFT_NWG % 8;
  const int xcd = orig & 7;
  const int wg = (xcd < r8 ? xcd * (q8 + 1) : r8 * (q8 + 1) + (xcd - r8) * q8) + (orig >> 3);
  const int bin0 = (wg & 3) * 128;
  const int m0   = (wg >> 2) * 256;

  // staging sources (pre-swizzled col; involution XOR on bits 4..6)
  const int srow = tid >> 3;          // 0..63 row within a 64-row quarter
  const int scol = (tid & 7) << 4;
  const unsigned char *gA0, *gA1, *gA2, *gA3, *gB0, *gB1, *gB2, *gB3;
  {
    int r0 = srow, r1 = 64 + srow, r2 = 128 + srow, r3 = 192 + srow;
    int m, bb, tt;
    m = m0 + r0; bb = m / 1000; tt = m - bb * 1000;
    gA0 = xpadb + ((size_t)bb * XPADL + (size_t)tt * HOP) * 2 + (scol ^ ((r0 & 7) << 4));
    m = m0 + r1; bb = m / 1000; tt = m - bb * 1000;
    gA1 = xpadb + ((size_t)bb * XPADL + (size_t)tt * HOP) * 2 + (scol ^ ((r1 & 7) << 4));
    m = m0 + r2; bb = m / 1000; tt = m - bb * 1000;
    gA2 = xpadb + ((size_t)bb * XPADL + (size_t)tt * HOP) * 2 + (scol ^ ((r2 & 7) << 4));
    m = m0 + r3; bb = m / 1000; tt = m - bb * 1000;
    gA3 = xpadb + ((size_t)bb * XPADL + (size_t)tt * HOP) * 2 + (scol ^ ((r3 & 7) << 4));
#define BROW(r) ((size_t)(bin0 + (((r) >> 5) << 4) + ((r) & 15) + ((((r) >> 4) & 1) * 513)) * 2048)
    gB0 = wbb + BROW(r0) + (scol ^ ((r0 & 7) << 4));
    gB1 = wbb + BROW(r1) + (scol ^ ((r1 & 7) << 4));
    gB2 = wbb + BROW(r2) + (scol ^ ((r2 & 7) << 4));
    gB3 = wbb + BROW(r3) + (scol ^ ((r3 & 7) << 4));
  }

#define LDSA(c, qq) ((void*)(lds + (c) * 32768 + (qq) * 8192 + w * 1024))
#define LDSB(c, qq) ((void*)(lds + 65536 + (c) * 32768 + (qq) * 8192 + w * 1024))
#define STG_ALL(c, kb) do {                                                \
    gload16(gA0 + (kb), LDSA(c, 0)); gload16(gA1 + (kb), LDSA(c, 1));      \
    gload16(gA2 + (kb), LDSA(c, 2)); gload16(gA3 + (kb), LDSA(c, 3));      \
    gload16(gB0 + (kb), LDSB(c, 0)); gload16(gB1 + (kb), LDSB(c, 1));      \
    gload16(gB2 + (kb), LDSB(c, 2)); gload16(gB3 + (kb), LDSB(c, 3));      \
  } while (0)

  // hoisted ds_read lane bases (row&7 == lane&7 -> phase-invariant XOR)
  const int xor0 = (((lane >> 4) << 4)) ^ ((lane & 7) << 4);
  const int xor1 = (64 + ((lane >> 4) << 4)) ^ ((lane & 7) << 4);
  const unsigned char* aB0 = lds + wm * 16384 + (lane & 15) * 128 + xor0;
  const unsigned char* aB1 = lds + wm * 16384 + (lane & 15) * 128 + xor1;
  const unsigned char* bB0 = lds + 65536 + wc * 8192 + (lane & 15) * 128 + xor0;
  const unsigned char* bB1 = lds + 65536 + wc * 8192 + (lane & 15) * 128 + xor1;

  bf16x8 af[8][2];   // [mf][ks]
  bf16x8 bfr[4][2];  // [nf][ks]
  f32x4 acc[8][4];
#pragma unroll
  for (int a = 0; a < 8; ++a)
#pragma unroll
    for (int b = 0; b < 4; ++b) acc[a][b] = (f32x4){0.f, 0.f, 0.f, 0.f};

#define RD_ALL(CCOFF) do {                                                 \
    _Pragma("unroll")                                                      \
    for (int mf_ = 0; mf_ < 8; ++mf_) {                                    \
      af[mf_][0] = *(const bf16x8*)(aB0 + (CCOFF) + mf_ * 2048);           \
      af[mf_][1] = *(const bf16x8*)(aB1 + (CCOFF) + mf_ * 2048);           \
    }                                                                      \
    _Pragma("unroll")                                                      \
    for (int nf_ = 0; nf_ < 4; ++nf_) {                                    \
      bfr[nf_][0] = *(const bf16x8*)(bB0 + (CCOFF) + nf_ * 2048);          \
      bfr[nf_][1] = *(const bf16x8*)(bB1 + (CCOFF) + nf_ * 2048);          \
    }                                                                      \
  } while (0)

#define MFMA_ALL() do {                                                    \
    __builtin_amdgcn_s_setprio(1);                                         \
    _Pragma("unroll")                                                      \
    for (int ks_ = 0; ks_ < 2; ++ks_)                                      \
      _Pragma("unroll")                                                    \
      for (int mf_ = 0; mf_ < 8; ++mf_)                                    \
        _Pragma("unroll")                                                  \
        for (int nf_ = 0; nf_ < 4; ++nf_)                                  \
          acc[mf_][nf_] = __builtin_amdgcn_mfma_f32_16x16x32_bf16(         \
              af[mf_][ks_], bfr[nf_][ks_], acc[mf_][nf_], 0, 0, 0);        \
    __builtin_amdgcn_s_setprio(0);                                         \
  } while (0)

  // prologue: stage k0->buf0, k1->buf1 (16 loads); retire k0
  STG_ALL(0, 0);
  STG_ALL(1, 128);
  WAIT_VM(8);
  BAR();

  for (int ii = 0; ii < 8; ++ii) {
    const bool more = (ii < 7);
    // ---- ktile 2ii (buf0) ----
    RD_ALL(0);
    WAIT_LGKM0;
    BAR();                                   // all waves done reading buf0
    if (more) STG_ALL(0, (size_t)(2 * ii + 2) * 128);
    MFMA_ALL();
    if (more) { WAIT_VM(8); } else { WAIT_VM(0); }
    BAR();                                   // next buffer's ktile landed
    // ---- ktile 2ii+1 (buf1) ----
    RD_ALL(32768);
    WAIT_LGKM0;
    BAR();
    if (more) STG_ALL(1, (size_t)(2 * ii + 3) * 128);
    MFMA_ALL();
    if (more) { WAIT_VM(8); BAR(); }
  }

  // epilogue: power = cos^2 + sin^2 (nf pairs (0,1),(2,3))
  const int col = lane & 15;
  const int rg  = lane >> 4;
#pragma unroll
  for (int mf_ = 0; mf_ < 8; ++mf_)
#pragma unroll
    for (int g = 0; g < 2; ++g) {
      int bin = bin0 + wc * 32 + g * 16 + col;
#pragma unroll
      for (int rr = 0; rr < 4; ++rr) {
        int m = m0 + wm * 128 + mf_ * 16 + rg * 4 + rr;
        float c = acc[mf_][2 * g][rr];
        float s = acc[mf_][2 * g + 1][rr];
        pw[(size_t)m * PWC + bin] = __float2bfloat16(c * c + s * s);
      }
    }
}

// ---------------- mel GEMM (K=512) + p512 rank-1 + log10 epilogue ----------------
__launch_bounds__(256, 2)
__global__ void mel_kernel(unsigned char* __restrict__ ws, const float* __restrict__ mfp) {
  __shared__ __align__(16) unsigned char sA[128 * 128];
  __shared__ __align__(16) unsigned char sBt[64 * 128];
  const unsigned char* pwb  = ws + PW_OFF;
  const unsigned char* wmtb = ws + WMT_OFF;
  const float* p5 = (const float*)(ws + P512_OFF);
  float* lm = (float*)(ws + LM_OFF);

  const int tid = threadIdx.x;
  const int lane = tid & 63;
  const int wid  = tid >> 6;
  const int m0 = blockIdx.x * 128;

  const int srow = lane >> 3;
  const int kb2  = (lane & 7) << 4;

  const unsigned char* aptr[4];
  unsigned char* aldst[4];
#pragma unroll
  for (int j = 0; j < 4; ++j) {
    int rr = wid * 32 + j * 8 + srow;
    aptr[j] = pwb + (size_t)(m0 + rr) * (PWC * 2) + (kb2 ^ ((rr & 7) << 4));
    aldst[j] = &sA[(wid * 32 + j * 8) * 128];
  }
  const unsigned char* bptr[2];
  unsigned char* bldst[2];
#pragma unroll
  for (int j = 0; j < 2; ++j) {
    int rr = wid * 16 + j * 8 + srow;
    bptr[j] = wmtb + (size_t)rr * (PWC * 2) + (kb2 ^ ((rr & 7) << 4));
    bldst[j] = &sBt[(wid * 16 + j * 8) * 128];
  }

  f32x4 acc[2][4];
#pragma unroll
  for (int mi = 0; mi < 2; ++mi)
#pragma unroll
    for (int fr = 0; fr < 4; ++fr) acc[mi][fr] = (f32x4){0.f, 0.f, 0.f, 0.f};

  for (int kk = 0; kk < PWC; kk += 64) {
    __syncthreads();
#pragma unroll
    for (int j = 0; j < 4; ++j) gload16(aptr[j] + (size_t)kk * 2, aldst[j]);
#pragma unroll
    for (int j = 0; j < 2; ++j) gload16(bptr[j] + (size_t)kk * 2, bldst[j]);
    __syncthreads();
#pragma unroll
    for (int ks = 0; ks < 2; ++ks) {
      const int kby = ks * 64 + ((lane >> 4) << 4);
      bf16x8 af[2], bfr[4];
#pragma unroll
      for (int mi = 0; mi < 2; ++mi) {
        int rr = wid * 32 + mi * 16 + (lane & 15);
        af[mi] = *(const bf16x8*)&sA[rr * 128 + (kby ^ ((rr & 7) << 4))];
      }
#pragma unroll
      for (int fr = 0; fr < 4; ++fr) {
        int rr = fr * 16 + (lane & 15);
        bfr[fr] = *(const bf16x8*)&sBt[rr * 128 + (kby ^ ((rr & 7) << 4))];
      }
#pragma unroll
      for (int mi = 0; mi < 2; ++mi)
#pragma unroll
        for (int fr = 0; fr < 4; ++fr)
          acc[mi][fr] = __builtin_amdgcn_mfma_f32_16x16x32_bf16(af[mi], bfr[fr], acc[mi][fr], 0, 0, 0);
    }
  }

  const int col = lane & 15;
  const int rg  = lane >> 4;
#pragma unroll
  for (int mi = 0; mi < 2; ++mi)
#pragma unroll
    for (int fr = 0; fr < 4; ++fr) {
      int n = fr * 16 + col;
      float f512 = mfp[512 * NMEL + n];
#pragma unroll
      for (int rr = 0; rr < 4; ++rr) {
        int mrow = wid * 32 + mi * 16 + rg * 4 + rr;
        float v = acc[mi][fr][rr] + p5[m0 + mrow] * f512;
        lm[(size_t)(m0 + mrow) * NMEL + n] = 10.0f * log10f(fmaxf(v, 1e-10f));
      }
    }
}

// ---------------- bilinear (time-axis only) interp ----------------
__global__ void interp_kernel(const unsigned char* __restrict__ ws, float* __restrict__ out) {
  const float* lm = (const float*)(ws + LM_OFF);
  int idx = blockIdx.x * blockDim.x + threadIdx.x;
  if (idx >= NBATCH * SPECW * 16) return;
  int m4 = idx & 15;
  int h  = (idx >> 4) & (SPECW - 1);
  int b  = idx >> 14;
  const float scale = (float)(999.0 / 1023.0);
  float pos = (float)h * scale;
  int i0 = (int)floorf(pos);
  if (i0 > TOUT - 1) i0 = TOUT - 1;
  float w = pos - (float)i0;
  int i1 = i0 + 1;
  if (i1 > TOUT - 1) i1 = TOUT - 1;
  const float4* r0 = (const float4*)(lm + ((size_t)b * TOUT + i0) * NMEL);
  const float4* r1 = (const float4*)(lm + ((size_t)b * TOUT + i1) * NMEL);
  float4 a = r0[m4], c = r1[m4];
  float4 o;
  o.x = a.x * (1.0f - w) + c.x * w;
  o.y = a.y * (1.0f - w) + c.y * w;
  o.z = a.z * (1.0f - w) + c.z * w;
  o.w = a.w * (1.0f - w) + c.w * w;
  ((float4*)out)[idx] = o;
}

extern "C" void kernel_launch(void* const* d_in, const int* in_sizes, int n_in,
                              void* d_out, int out_size, void* d_ws, size_t ws_size,
                              hipStream_t stream) {
  (void)in_sizes; (void)n_in; (void)out_size; (void)ws_size;
  const float* wav   = (const float*)d_in[0];
  const float* wstft = (const float*)d_in[1];
  const float* mf    = (const float*)d_in[2];
  unsigned char* ws  = (unsigned char*)d_ws;
  float* out = (float*)d_out;

  const int tot = NV1 + NV2 + NV3;
  prep_kernel<<<(tot + 255) / 256, 256, 0, stream>>>(wav, wstft, mf, ws);
  p512_kernel<<<NBATCH * 16, 256, 0, stream>>>(ws);
  stft_kernel<<<STFT_NWG, 512, 0, stream>>>(ws);
  mel_kernel<<<250, 256, 0, stream>>>(ws, mf);
  interp_kernel<<<(NBATCH * SPECW * 16) / 256, 256, 0, stream>>>(ws, out);
}

// Round 7
// 110.481 us; speedup vs baseline: 4.6456x; 1.1794x over previous
//
#include <hip/hip_runtime.h>
#include <hip/hip_bf16.h>

#define LWAV   480000
#define XPADL  481024
#define NBATCH 32
#define TOUT   1000
#define NFFT   1024
#define NBINS  513
#define NMEL   64
#define PWC    512
#define SPECW  1024
#define HOP    480

// workspace layout (bytes), 256-aligned
#define XPAD_OFF 0u           // 32*481024*2   = 30,785,536
#define WB_OFF   30785536u    // 1026*1024*2   =  2,101,248
#define WMT_OFF  32886784u    // 64*512*2      =     65,536
#define PW_OFF   32952320u    // 32000*512*2   = 32,768,000
#define LM_OFF   65720320u    // 32000*64*4    =  8,192,000
#define P512_OFF 73912320u    // 32000*4       =    128,000  -> end 74,040,320

typedef __attribute__((ext_vector_type(8))) __bf16 bf16x8;
typedef __attribute__((ext_vector_type(8))) unsigned short ushort8;
typedef __attribute__((ext_vector_type(4))) float  f32x4;
typedef __attribute__((ext_vector_type(16))) float f32x16;

__device__ __forceinline__ void gload16(const void* g, void* l) {
  __builtin_amdgcn_global_load_lds((const __attribute__((address_space(1))) void*)g,
                                   (__attribute__((address_space(3))) void*)l, 16, 0, 0);
}

#define WAIT_VM(n)  asm volatile("s_waitcnt vmcnt(" #n ")" ::: "memory")
#define BAR() __builtin_amdgcn_s_barrier()

__device__ __forceinline__ float bf2f(unsigned short u) {
  return __uint_as_float((unsigned)u << 16);
}

// ---------------- prepass ----------------
#define NV1 (NBATCH * (XPADL / 8))          // 1,924,096
#define NV2 ((1026 * NFFT) / 8)             //   131,328
#define NV3 ((NMEL * PWC) / 8)              //     4,096

__global__ void prep_kernel(const float* __restrict__ wav,
                            const float* __restrict__ wstft,
                            const float* __restrict__ mf,
                            unsigned char* __restrict__ ws) {
  __hip_bfloat16* xpad = (__hip_bfloat16*)(ws + XPAD_OFF);
  __hip_bfloat16* wb   = (__hip_bfloat16*)(ws + WB_OFF);
  __hip_bfloat16* wmt  = (__hip_bfloat16*)(ws + WMT_OFF);
  int idx = blockIdx.x * blockDim.x + threadIdx.x;
  if (idx < NV1) {
    int b  = idx / (XPADL / 8);
    int pg = (idx - b * (XPADL / 8)) * 8;
    __hip_bfloat16* dst = xpad + (size_t)b * XPADL + pg;
    const float* src = wav + (size_t)b * LWAV;
    if (pg >= 512 && pg <= LWAV + 496) {
      float4 v0 = *(const float4*)(src + pg - 512);
      float4 v1 = *(const float4*)(src + pg - 508);
      __hip_bfloat16 t[8];
      t[0] = __float2bfloat16(v0.x); t[1] = __float2bfloat16(v0.y);
      t[2] = __float2bfloat16(v0.z); t[3] = __float2bfloat16(v0.w);
      t[4] = __float2bfloat16(v1.x); t[5] = __float2bfloat16(v1.y);
      t[6] = __float2bfloat16(v1.z); t[7] = __float2bfloat16(v1.w);
      *(uint4*)dst = *(const uint4*)t;
    } else {
      for (int j = 0; j < 8; ++j) {
        int s = pg + j - 512;
        if (s < 0) s = -s;
        else if (s >= LWAV) s = 2 * (LWAV - 1) - s;
        dst[j] = __float2bfloat16(src[s]);
      }
    }
  } else if (idx < NV1 + NV2) {
    int g = (idx - NV1) * 8;
    float4 v0 = *(const float4*)(wstft + g);
    float4 v1 = *(const float4*)(wstft + g + 4);
    __hip_bfloat16 t[8];
    t[0] = __float2bfloat16(v0.x); t[1] = __float2bfloat16(v0.y);
    t[2] = __float2bfloat16(v0.z); t[3] = __float2bfloat16(v0.w);
    t[4] = __float2bfloat16(v1.x); t[5] = __float2bfloat16(v1.y);
    t[6] = __float2bfloat16(v1.z); t[7] = __float2bfloat16(v1.w);
    *(uint4*)(wb + g) = *(const uint4*)t;
  } else if (idx < NV1 + NV2 + NV3) {
    int j  = idx - NV1 - NV2;
    int n  = j / (PWC / 8);
    int k0 = (j - n * (PWC / 8)) * 8;
    for (int k = k0; k < k0 + 8; ++k)
      wmt[n * PWC + k] = __float2bfloat16(mf[k * NMEL + n]);
  }
}

// ---------------- p512: power of bin 512 per frame (direct L2/L3 reads) ----------------
__launch_bounds__(256, 4)
__global__ void p512_kernel(unsigned char* __restrict__ ws) {
  const unsigned char* xpadb = ws + XPAD_OFF;
  const unsigned char* wbb   = ws + WB_OFF;
  float* out = (float*)(ws + P512_OFF);

  const int tid  = threadIdx.x;
  const int b    = blockIdx.x >> 4;
  const int tile = blockIdx.x & 15;
  const int t0   = tile * 64;
  const int nf   = (tile == 15) ? 40 : 64;

  const int lane = tid & 63;
  const int wv   = tid >> 6;
  const int kc   = lane & 15;
  const int fg   = lane >> 4;
  const unsigned char* wc_base = wbb + (size_t)512  * 2048 + kc * 16;
  const unsigned char* ws_base = wbb + (size_t)1025 * 2048 + kc * 16;
#pragma unroll
  for (int pass = 0; pass < 4; ++pass) {
    int fr = pass * 16 + wv * 4 + fg;
    if (fr < nf) {
      const unsigned char* xp = xpadb + ((size_t)b * XPADL + (size_t)(t0 + fr) * HOP) * 2 + kc * 16;
      float dc = 0.f, dsn = 0.f;
#pragma unroll
      for (int j = 0; j < 8; ++j) {
        ushort8 a  = *(const ushort8*)(xp + j * 256);
        ushort8 uc = *(const ushort8*)(wc_base + j * 256);
        ushort8 us = *(const ushort8*)(ws_base + j * 256);
#pragma unroll
        for (int e = 0; e < 8; ++e) {
          float fa = bf2f(a[e]);
          dc  += fa * bf2f(uc[e]);
          dsn += fa * bf2f(us[e]);
        }
      }
#pragma unroll
      for (int d = 1; d < 16; d <<= 1) {
        dc  += __shfl_xor(dc, d);
        dsn += __shfl_xor(dsn, d);
      }
      if (kc == 0)
        out[(size_t)b * TOUT + t0 + fr] = dc * dc + dsn * dsn;
    }
  }
}

// ---------------- STFT: 256x256, 32x32x16 MFMA, barrier-free inner ktile ----
// BM=256 frames, BN=256 weight rows (128 bins x {cos,sin}: tile row n -> bin =
// bin0+(n>>6)*32+(n&31), part=(n>>5)&1). 8 waves (2M x 4N), BK=64, 16 ktiles,
// dbuf LDS 128 KiB. Per ktile: rolling 2-set frag pipeline over ks=0..3 with
// MFMA interleaved between ds_reads (compiler emits fine-grained lgkmcnt ->
// LDS latency hides under MFMA within the wave, no read/MFMA lockstep).
// Barriers only at ktile end: BAR; STG(k+2 -> this buf); vmcnt(8); BAR.
#define STFT_NWG 500
__launch_bounds__(512, 1)
__global__ void stft_kernel(unsigned char* __restrict__ ws) {
  __shared__ __align__(16) unsigned char lds[131072];  // A: c*32768; B: 65536+c*32768
  const unsigned char* xpadb = ws + XPAD_OFF;
  const unsigned char* wbb   = ws + WB_OFF;
  __hip_bfloat16* pw = (__hip_bfloat16*)(ws + PW_OFF);

  const int tid  = threadIdx.x;
  const int lane = tid & 63;
  const int w    = tid >> 6;
  const int wm   = w >> 2;     // 0..1 (m half, 128 rows)
  const int wc   = w & 3;      // 0..3 (n quad, 64 rows = 32 bins cos+sin)

  // bijective XCD-chunked swizzle (nwg=500: q=62, r=4), n-tile fastest
  const int orig = blockIdx.x;
  const int q8 = STFT_NWG / 8, r8 = STFT_NWG % 8;
  const int xcd = orig & 7;
  const int wg = (xcd < r8 ? xcd * (q8 + 1) : r8 * (q8 + 1) + (xcd - r8) * q8) + (orig >> 3);
  const int bin0 = (wg & 3) * 128;
  const int m0   = (wg >> 2) * 256;

  // staging sources (pre-swizzled col; involution XOR on bits 4..6)
  const int srow = tid >> 3;          // 0..63 row within a 64-row quarter
  const int scol = (tid & 7) << 4;
  const unsigned char *gA0, *gA1, *gA2, *gA3, *gB0, *gB1, *gB2, *gB3;
  {
    int r0 = srow, r1 = 64 + srow, r2 = 128 + srow, r3 = 192 + srow;
    int m, bb, tt;
    m = m0 + r0; bb = m / 1000; tt = m - bb * 1000;
    gA0 = xpadb + ((size_t)bb * XPADL + (size_t)tt * HOP) * 2 + (scol ^ ((r0 & 7) << 4));
    m = m0 + r1; bb = m / 1000; tt = m - bb * 1000;
    gA1 = xpadb + ((size_t)bb * XPADL + (size_t)tt * HOP) * 2 + (scol ^ ((r1 & 7) << 4));
    m = m0 + r2; bb = m / 1000; tt = m - bb * 1000;
    gA2 = xpadb + ((size_t)bb * XPADL + (size_t)tt * HOP) * 2 + (scol ^ ((r2 & 7) << 4));
    m = m0 + r3; bb = m / 1000; tt = m - bb * 1000;
    gA3 = xpadb + ((size_t)bb * XPADL + (size_t)tt * HOP) * 2 + (scol ^ ((r3 & 7) << 4));
    // tile row n -> weight row: bin0 + (n>>6)*32 + (n&31) + ((n>>5)&1)*513
#define BROW(r) ((size_t)(bin0 + (((r) >> 6) << 5) + ((r) & 31) + ((((r) >> 5) & 1) * 513)) * 2048)
    gB0 = wbb + BROW(r0) + (scol ^ ((r0 & 7) << 4));
    gB1 = wbb + BROW(r1) + (scol ^ ((r1 & 7) << 4));
    gB2 = wbb + BROW(r2) + (scol ^ ((r2 & 7) << 4));
    gB3 = wbb + BROW(r3) + (scol ^ ((r3 & 7) << 4));
  }

#define LDSA(c, qq) ((void*)(lds + (c) * 32768 + (qq) * 8192 + w * 1024))
#define LDSB(c, qq) ((void*)(lds + 65536 + (c) * 32768 + (qq) * 8192 + w * 1024))
#define STG_ALL(c, kb) do {                                                \
    gload16(gA0 + (kb), LDSA(c, 0)); gload16(gA1 + (kb), LDSA(c, 1));      \
    gload16(gA2 + (kb), LDSA(c, 2)); gload16(gA3 + (kb), LDSA(c, 3));      \
    gload16(gB0 + (kb), LDSB(c, 0)); gload16(gB1 + (kb), LDSB(c, 1));      \
    gload16(gB2 + (kb), LDSB(c, 2)); gload16(gB3 + (kb), LDSB(c, 3));      \
  } while (0)

  // per-lane 32x32x16 fragment read offsets; row = base + (lane&31),
  // kchunk = lane>>5; row&7 == lane&7 so the XOR pattern is lane-invariant.
  int aoff[4], boff[4];
#pragma unroll
  for (int ks = 0; ks < 4; ++ks) {
    int kb = ks * 32 + ((lane >> 5) << 4);
    int sw = (lane & 7) << 4;
    aoff[ks] = wm * 16384 + (lane & 31) * 128 + (kb ^ sw);
    boff[ks] = 65536 + wc * 8192 + (lane & 31) * 128 + (kb ^ sw);
  }

  bf16x8 afA[4], bfA[2], afB[4], bfB[2];
  f32x16 acc[4][2];   // [mf][cos/sin]
#pragma unroll
  for (int a = 0; a < 4; ++a)
#pragma unroll
    for (int b = 0; b < 2; ++b)
#pragma unroll
      for (int e = 0; e < 16; ++e) acc[a][b][e] = 0.f;

#define RDF(CCOFF, KS, A, B) do {                                          \
    _Pragma("unroll")                                                      \
    for (int mf_ = 0; mf_ < 4; ++mf_)                                      \
      A[mf_] = *(const bf16x8*)(lds + (CCOFF) + mf_ * 4096 + aoff[KS]);    \
    _Pragma("unroll")                                                      \
    for (int nf_ = 0; nf_ < 2; ++nf_)                                      \
      B[nf_] = *(const bf16x8*)(lds + (CCOFF) + nf_ * 4096 + boff[KS]);    \
  } while (0)

#define MM(A, B) do {                                                      \
    __builtin_amdgcn_s_setprio(1);                                         \
    _Pragma("unroll")                                                      \
    for (int mf_ = 0; mf_ < 4; ++mf_) {                                    \
      acc[mf_][0] = __builtin_amdgcn_mfma_f32_32x32x16_bf16(               \
          A[mf_], B[0], acc[mf_][0], 0, 0, 0);                             \
      acc[mf_][1] = __builtin_amdgcn_mfma_f32_32x32x16_bf16(               \
          A[mf_], B[1], acc[mf_][1], 0, 0, 0);                             \
    }                                                                      \
    __builtin_amdgcn_s_setprio(0);                                         \
  } while (0)

#define KT_BODY(CCOFF) do {                                                \
    RDF(CCOFF, 0, afA, bfA);                                               \
    RDF(CCOFF, 1, afB, bfB);                                               \
    MM(afA, bfA);                                                          \
    RDF(CCOFF, 2, afA, bfA);                                               \
    MM(afB, bfB);                                                          \
    RDF(CCOFF, 3, afB, bfB);                                               \
    MM(afA, bfA);                                                          \
    MM(afB, bfB);                                                          \
  } while (0)

  // prologue: stage k0->buf0, k1->buf1 (16 loads); retire k0
  STG_ALL(0, 0);
  STG_ALL(1, 128);
  WAIT_VM(8);
  BAR();

  for (int ii = 0; ii < 8; ++ii) {
    // ---- ktile 2ii (buf0) ----
    KT_BODY(0);
    BAR();                                    // all waves done reading buf0
    if (ii < 7) {
      STG_ALL(0, (size_t)(2 * ii + 2) * 128); // overwrite buf0 with k(2ii+2)
      WAIT_VM(8);                             // retire k(2ii+1) -> buf1 ready
    } else {
      WAIT_VM(0);                             // retire k15
    }
    BAR();
    // ---- ktile 2ii+1 (buf1) ----
    KT_BODY(32768);
    if (ii < 7) {
      BAR();
      STG_ALL(1, (size_t)(2 * ii + 3) * 128);
      WAIT_VM(8);
      BAR();
    }
  }

  // epilogue: power = cos^2 + sin^2; 32x32 C/D: col=lane&31,
  // row=(reg&3)+8*(reg>>2)+4*(lane>>5)
  const int bin = bin0 + wc * 32 + (lane & 31);
  const int rbase = m0 + wm * 128 + ((lane >> 5) << 2);
#pragma unroll
  for (int mf_ = 0; mf_ < 4; ++mf_)
#pragma unroll
    for (int reg = 0; reg < 16; ++reg) {
      int m = rbase + mf_ * 32 + (reg & 3) + ((reg >> 2) << 3);
      float c = acc[mf_][0][reg];
      float s = acc[mf_][1][reg];
      pw[(size_t)m * PWC + bin] = __float2bfloat16(c * c + s * s);
    }
}

// ---------------- mel GEMM (K=512, BM=64) + p512 rank-1 + log10 epilogue ----------------
__launch_bounds__(256, 4)
__global__ void mel_kernel(unsigned char* __restrict__ ws, const float* __restrict__ mfp) {
  __shared__ __align__(16) unsigned char sA[64 * 128];
  __shared__ __align__(16) unsigned char sBt[64 * 128];
  const unsigned char* pwb  = ws + PW_OFF;
  const unsigned char* wmtb = ws + WMT_OFF;
  const float* p5 = (const float*)(ws + P512_OFF);
  float* lm = (float*)(ws + LM_OFF);

  const int tid = threadIdx.x;
  const int lane = tid & 63;
  const int wid  = tid >> 6;
  const int m0 = blockIdx.x * 64;

  const int strow = tid >> 3;        // 0..31 row within 32-row shot
  const int scol  = (tid & 7) << 4;

  const unsigned char* aptr[2];
  const unsigned char* bptr[2];
  unsigned char* aldst[2];
  unsigned char* bldst[2];
#pragma unroll
  for (int j = 0; j < 2; ++j) {
    int rr = j * 32 + strow;
    aptr[j] = pwb + (size_t)(m0 + rr) * (PWC * 2) + (scol ^ ((rr & 7) << 4));
    bptr[j] = wmtb + (size_t)rr * (PWC * 2) + (scol ^ ((rr & 7) << 4));
    aldst[j] = &sA [j * 4096 + wid * 1024];
    bldst[j] = &sBt[j * 4096 + wid * 1024];
  }

  f32x4 acc[4];
#pragma unroll
  for (int fr = 0; fr < 4; ++fr) acc[fr] = (f32x4){0.f, 0.f, 0.f, 0.f};

  for (int kk = 0; kk < PWC; kk += 64) {
    __syncthreads();
#pragma unroll
    for (int j = 0; j < 2; ++j) gload16(aptr[j] + (size_t)kk * 2, aldst[j]);
#pragma unroll
    for (int j = 0; j < 2; ++j) gload16(bptr[j] + (size_t)kk * 2, bldst[j]);
    __syncthreads();
#pragma unroll
    for (int ks = 0; ks < 2; ++ks) {
      const int kby = ks * 64 + ((lane >> 4) << 4);
      bf16x8 af, bfr[4];
      {
        int rr = wid * 16 + (lane & 15);
        af = *(const bf16x8*)&sA[rr * 128 + (kby ^ ((rr & 7) << 4))];
      }
#pragma unroll
      for (int fr = 0; fr < 4; ++fr) {
        int rr = fr * 16 + (lane & 15);
        bfr[fr] = *(const bf16x8*)&sBt[rr * 128 + (kby ^ ((rr & 7) << 4))];
      }
#pragma unroll
      for (int fr = 0; fr < 4; ++fr)
        acc[fr] = __builtin_amdgcn_mfma_f32_16x16x32_bf16(af, bfr[fr], acc[fr], 0, 0, 0);
    }
  }

  const int col = lane & 15;
  const int rg  = lane >> 4;
#pragma unroll
  for (int fr = 0; fr < 4; ++fr) {
    int n = fr * 16 + col;
    float f512 = mfp[512 * NMEL + n];
#pragma unroll
    for (int rr = 0; rr < 4; ++rr) {
      int mrow = wid * 16 + rg * 4 + rr;
      float v = acc[fr][rr] + p5[m0 + mrow] * f512;
      lm[(size_t)(m0 + mrow) * NMEL + n] = 10.0f * log10f(fmaxf(v, 1e-10f));
    }
  }
}

// ---------------- bilinear (time-axis only) interp ----------------
__global__ void interp_kernel(const unsigned char* __restrict__ ws, float* __restrict__ out) {
  const float* lm = (const float*)(ws + LM_OFF);
  int idx = blockIdx.x * blockDim.x + threadIdx.x;
  if (idx >= NBATCH * SPECW * 16) return;
  int m4 = idx & 15;
  int h  = (idx >> 4) & (SPECW - 1);
  int b  = idx >> 14;
  const float scale = (float)(999.0 / 1023.0);
  float pos = (float)h * scale;
  int i0 = (int)floorf(pos);
  if (i0 > TOUT - 1) i0 = TOUT - 1;
  float w = pos - (float)i0;
  int i1 = i0 + 1;
  if (i1 > TOUT - 1) i1 = TOUT - 1;
  const float4* r0 = (const float4*)(lm + ((size_t)b * TOUT + i0) * NMEL);
  const float4* r1 = (const float4*)(lm + ((size_t)b * TOUT + i1) * NMEL);
  float4 a = r0[m4], c = r1[m4];
  float4 o;
  o.x = a.x * (1.0f - w) + c.x * w;
  o.y = a.y * (1.0f - w) + c.y * w;
  o.z = a.z * (1.0f - w) + c.z * w;
  o.w = a.w * (1.0f - w) + c.w * w;
  ((float4*)out)[idx] = o;
}

extern "C" void kernel_launch(void* const* d_in, const int* in_sizes, int n_in,
                              void* d_out, int out_size, void* d_ws, size_t ws_size,
                              hipStream_t stream) {
  (void)in_sizes; (void)n_in; (void)out_size; (void)ws_size;
  const float* wav   = (const float*)d_in[0];
  const float* wstft = (const float*)d_in[1];
  const float* mf    = (const float*)d_in[2];
  unsigned char* ws  = (unsigned char*)d_ws;
  float* out = (float*)d_out;

  const int tot = NV1 + NV2 + NV3;
  prep_kernel<<<(tot + 255) / 256, 256, 0, stream>>>(wav, wstft, mf, ws);
  p512_kernel<<<NBATCH * 16, 256, 0, stream>>>(ws);
  stft_kernel<<<STFT_NWG, 512, 0, stream>>>(ws);
  mel_kernel<<<500, 256, 0, stream>>>(ws, mf);
  interp_kernel<<<(NBATCH * SPECW * 16) / 256, 256, 0, stream>>>(ws, out);
}